// Round 7
// baseline (403.183 us; speedup 1.0000x reference)
//
#include <hip/hip_runtime.h>
#include <math.h>

// Problem constants (from reference)
#define NWG   16          // NW groups
#define NSTEP 16          // 1 + NG + NF sequences per group
#define NGE   5
#define T_LEN 400
#define DIM   64
#define GAMMA 5.0f
#define BIGV  1e10f

#define BLOCK 448         // 7 waves; lane slot iA = 63*w + l (1-lane halo/wave)

// ---------------------------------------------------------------------------
// Fused cost + soft-DTW wavefront, one block per (anchor, seq) pair.
// 2x1 column-pair blocking: per phase (diags k, k+1) each lane computes
//   cellA = (iA,   jA) on diag k     (jA = k - iA)
//   cellB = (iA+1, jA) on diag k+1   (same column -> SAME B row jA-1)
// -> one 256B LDS B-row read feeds two cells; one barrier per 2 diagonals.
// A rows iA-1 (for cellA) and iA (for cellB) live in registers (128 VGPR).
// cellB deps: p2 = cellA's p1v (reg reuse), p1s = own vA (reg),
//             p1v = cellA of lane l+1 (intra-wave __shfl_down; halo layout
//             guarantees the neighbor is in the same wave).
// 4 rotating diag buffers Rbuf[d&3]; read {k-1,k-2} / write {k,k+1} disjoint.
// Sub-rectangle [1..la]x[1..lb] masking (dependency-closed; boundary = BIG
// exactly as reference init d0/d1), loop ends at diag la+lb.
// ---------------------------------------------------------------------------
__launch_bounds__(BLOCK, 2)
__global__ void sdtw_kernel(const float* __restrict__ data,
                            const int* __restrict__ lens,
                            float* __restrict__ dists)
{
    __shared__ float Blds[T_LEN * DIM];        // 102,400 B (swizzled)
    __shared__ float bnorm[T_LEN];             // 1,600 B
    __shared__ float Rbuf[4][T_LEN + 1];       // 6,416 B

    const int p   = blockIdx.x;
    const int tid = threadIdx.x;
    const int w   = tid >> 6;
    const int l   = tid & 63;
    const int iA  = 63 * w + l;        // cellA row; 0 => boundary row R[0][*]
    const int anchor = (p / NSTEP) * NSTEP;

    const float* __restrict__ Bg = data + (size_t)p      * (T_LEN * DIM);
    const float* __restrict__ Ag = data + (size_t)anchor * (T_LEN * DIM);

    // ---- stage B into LDS (coalesced global read, swizzled LDS write) ----
    for (int idx = tid; idx < T_LEN * (DIM / 4); idx += BLOCK) {
        const int c  = idx >> 4;       // B row
        const int cc = idx & 15;       // 16B chunk within row
        const float4 v = reinterpret_cast<const float4*>(Bg)[idx];
        const int x  = cc ^ (c & 7);   // swizzled chunk
        *reinterpret_cast<float4*>(&Blds[c * DIM + x * 4]) = v;
    }

    // ---- A rows iA-1 (cellA) and iA (cellB) into registers + norms ----
    float4 Aa[16], Ab[16];
    float  anA = 0.f, anB = 0.f;
    {
        const int ra = min(max(iA - 1, 0), T_LEN - 1);   // clamp: inactive lanes
        const int rb = min(iA, T_LEN - 1);
        const float4* __restrict__ pa =
            reinterpret_cast<const float4*>(Ag + (size_t)ra * DIM);
        const float4* __restrict__ pb =
            reinterpret_cast<const float4*>(Ag + (size_t)rb * DIM);
        #pragma unroll
        for (int cc = 0; cc < 16; ++cc) {
            Aa[cc] = pa[cc];
            Ab[cc] = pb[cc];
            anA += Aa[cc].x*Aa[cc].x + Aa[cc].y*Aa[cc].y
                 + Aa[cc].z*Aa[cc].z + Aa[cc].w*Aa[cc].w;
            anB += Ab[cc].x*Ab[cc].x + Ab[cc].y*Ab[cc].y
                 + Ab[cc].z*Ab[cc].z + Ab[cc].w*Ab[cc].w;
        }
    }
    __syncthreads();   // B resident

    // ---- ||B_c||^2 from LDS (lane c reads its own row; conflict-free) ----
    if (tid < T_LEN) {
        const int c = tid;
        float s = 0.f;
        #pragma unroll
        for (int cc = 0; cc < 16; ++cc) {
            const float4 b = *reinterpret_cast<const float4*>(
                &Blds[c * DIM + ((cc ^ (c & 7)) * 4)]);
            s += b.x*b.x + b.y*b.y + b.z*b.z + b.w*b.w;
        }
        bnorm[c] = s;
    }

    // ---- init diag buffers 0 (R[0][0]=0, rest BIG) and 1 (all BIG) ----
    for (int idx = tid; idx <= T_LEN; idx += BLOCK) {
        Rbuf[0][idx] = (idx == 0) ? 0.f : BIGV;
        Rbuf[1][idx] = BIGV;
    }
    __syncthreads();

    const int la = lens[anchor];       // [200, 400]
    const int lb = lens[p];
    const int kt = la + lb;            // target diag, [400, 800]
    const int P  = kt >> 1;            // phases: diags (2, 3) .. (2P, 2P+1)
    float saved = 0.f;
    bool  have  = false;
    const float NIG = -1.0f / GAMMA;

    for (int ph = 1; ph <= P; ++ph) {
        const int  k     = 2 * ph;                 // cellA diag (cellB: k+1)
        const int  c     = k - iA - 1;             // shared B row = jA-1 = jB-1
        const bool colOK = (c >= 0) && (c < lb);
        const bool aAct  = colOK && (iA >= 1) && (iA <= la);
        const bool bAct  = colOK && (l < 63) && (iA + 1 <= la);

        float p1vr = BIGV;       // R[iA][k-1-iA]: cellA p1v AND cellB p2
        float dA = 0.f, dB = 0.f, bn = 0.f;
        if (aAct || bAct) {      // exec-masked: fully-inactive waves skip
            p1vr = Rbuf[(k - 1) & 3][iA];
            bn   = bnorm[c];
            const float* __restrict__ Brow = &Blds[c * DIM];
            const int xr = (c & 7) * 4;            // float-index XOR swizzle
            #pragma unroll
            for (int cc = 0; cc < 16; ++cc) {
                const float4 b = *reinterpret_cast<const float4*>(&Brow[(cc * 4) ^ xr]);
                dA = fmaf(Aa[cc].x, b.x, dA); dB = fmaf(Ab[cc].x, b.x, dB);
                dA = fmaf(Aa[cc].y, b.y, dA); dB = fmaf(Ab[cc].y, b.y, dB);
                dA = fmaf(Aa[cc].z, b.z, dA); dB = fmaf(Ab[cc].z, b.z, dB);
                dA = fmaf(Aa[cc].w, b.w, dA); dB = fmaf(Ab[cc].w, b.w, dB);
            }
        }

        float vA = BIGV;
        if (aAct) {
            const float p2s = Rbuf[(k - 2) & 3][iA - 1];   // R[iA-1][jA-1]
            const float p1s = Rbuf[(k - 1) & 3][iA - 1];   // R[iA-1][jA]
            const float a  = p2s  * NIG;
            const float b2 = p1s  * NIG;
            const float c2 = p1vr * NIG;
            float m = fmaxf(fmaxf(a, b2), c2);
            float s = __expf(a - m) + __expf(b2 - m) + __expf(c2 - m);
            vA = (anA + bn - 2.f * dA) - GAMMA * (__logf(s) + m);
        }

        // wave-uniform shuffle: lane l receives vA of lane l+1
        // (= cellA of row iA+1 = R[iB][jB-1]); vA defined (BIG) on all lanes.
        const float vAn = __shfl_down(vA, 1);

        float vB = BIGV;
        if (bAct) {
            // cellB (iA+1, jB): p2 = p1vr, p1s = own vA, p1v = vAn
            const float a  = p1vr * NIG;
            const float b2 = vA   * NIG;
            const float c2 = vAn  * NIG;
            float m = fmaxf(fmaxf(a, b2), c2);
            float s = __expf(a - m) + __expf(b2 - m) + __expf(c2 - m);
            vB = (anB + bn - 2.f * dB) - GAMMA * (__logf(s) + m);
        }

        // capture R[la][lb] (unique primary rep: l < 63)
        if (k == kt     && iA == la     && l < 63) { saved = vA; have = true; }
        if (k + 1 == kt && iA + 1 == la && l < 63) { saved = vB; have = true; }

        // write-back (write buffers {k&3,(k+1)&3} disjoint from read buffers)
        if (iA <= T_LEN)               Rbuf[k & 3][iA] = vA;          // iA=0 -> BIG
        if (l < 63 && iA + 1 <= T_LEN) Rbuf[(k + 1) & 3][iA + 1] = vB;
        if (tid == BLOCK - 1)          Rbuf[(k + 1) & 3][0] = BIGV;   // R[0][k+1]
        __syncthreads();
    }

    if (have) dists[p] = saved / (float)kt;
}

// ---------------------------------------------------------------------------
// Loss epilogue (one wave). Exact-zero semantics of `nz` preserved.
// ---------------------------------------------------------------------------
__global__ void loss_kernel(const float* __restrict__ dists,
                            const float* __restrict__ margin,
                            float* __restrict__ out)
{
    const int g = threadIdx.x;
    float lv = 0.f;
    if (g < NWG) {
        const float* __restrict__ d = dists + g * NSTEP;
        const float aa = d[0];
        const float mg = margin[0];
        float s = 0.f;
        int   nz = 1;
        #pragma unroll
        for (int j = 1; j <= NGE; ++j) {
            const float v = d[j] - aa;
            s += v;
            nz += (v != 0.f);
        }
        #pragma unroll
        for (int j = 1 + NGE; j < NSTEP; ++j) {
            float v = mg - (d[j] - aa);
            v = fmaxf(v, 0.f);
            s += v;
            nz += (v != 0.f);
        }
        lv = s / (float)nz;
    }
    lv += __shfl_down(lv, 8);
    lv += __shfl_down(lv, 4);
    lv += __shfl_down(lv, 2);
    lv += __shfl_down(lv, 1);
    if (g == 0) out[0] = lv / (float)NWG;
}

extern "C" void kernel_launch(void* const* d_in, const int* in_sizes, int n_in,
                              void* d_out, int out_size, void* d_ws, size_t ws_size,
                              hipStream_t stream) {
    const float* data   = (const float*)d_in[0];
    const float* margin = (const float*)d_in[1];
    const int*   lens   = (const int*)d_in[2];
    float* dists = (float*)d_ws;          // 256 floats of scratch

    sdtw_kernel<<<NWG * NSTEP, BLOCK, 0, stream>>>(data, lens, dists);
    loss_kernel<<<1, 64, 0, stream>>>(dists, margin, (float*)d_out);
}

// Round 8
// 376.773 us; speedup vs baseline: 1.0701x; 1.0701x over previous
//
#include <hip/hip_runtime.h>
#include <math.h>

// Problem constants (from reference)
#define NWG   16          // NW groups
#define NSTEP 16          // 1 + NG + NF sequences per group
#define NGE   5
#define T_LEN 400
#define DIM   64
#define GAMMA 5.0f
#define BIGV  1e10f

#define BLOCK 448         // 7 waves; base row r = 62*w + l - 1 (2-lane halo)

// ---------------------------------------------------------------------------
// Fused cost + soft-DTW wavefront, one block per (anchor, seq) pair.
// 3x1 column blocking: per phase (diags k,k+1,k+2; k=3ph-1) each lane computes
//   cellA = (r,   j) on diag k     (j = k - r)
//   cellB = (r+1, j) on diag k+1   (same column)
//   cellC = (r+2, j) on diag k+2   (same column -> ONE 256B B-row read / 3 cells)
// Deps (derived & audited):
//   cellA: Rbuf[k-2][r-1], Rbuf[k-1][r-1], Rbuf[k-1][r]   (LDS, as before)
//   cellB: p1vr (reg), own vA (reg), shfl_down(vA,1)
//   cellC: shfl_down(vA,1), own vB, shfl_down(vB,1)       (no extra LDS)
// Halo: lanes l=62,63 duplicate next wave's l=0,1 (identical inputs);
//   writes/captures restricted to l<62. vB valid l<=62, vC valid l<=61 —
//   all consumed values valid.  Base r=-1 lane produces row-boundary cells
//   (incl. row 1 of diag k+2 via its cellC).
// 8 rotating diag buffers Rbuf[d&7]: write {k,k+1,k+2} disjoint from
// read {k-1,k-2} mod 8. One barrier per 3 diagonals.
// Sub-rectangle [1..la]x[1..lb] masking (dependency-closed; outside = BIG,
// matching reference d0/d1 init), loop ends at diag >= la+lb.
// ---------------------------------------------------------------------------
__launch_bounds__(BLOCK, 2)
__global__ void sdtw_kernel(const float* __restrict__ data,
                            const int* __restrict__ lens,
                            float* __restrict__ dists)
{
    __shared__ float Blds[T_LEN * DIM];        // 102,400 B (swizzled)
    __shared__ float bnorm[T_LEN];             // 1,600 B
    __shared__ float Rbuf[8][T_LEN + 1];       // 12,832 B

    const int p   = blockIdx.x;
    const int tid = threadIdx.x;
    const int w   = tid >> 6;
    const int l   = tid & 63;
    const int r   = 62 * w + l - 1;    // base row; -1 => boundary-producing lane
    const int anchor = (p / NSTEP) * NSTEP;

    const float* __restrict__ Bg = data + (size_t)p      * (T_LEN * DIM);
    const float* __restrict__ Ag = data + (size_t)anchor * (T_LEN * DIM);

    // ---- stage B into LDS (coalesced global read, swizzled LDS write) ----
    for (int idx = tid; idx < T_LEN * (DIM / 4); idx += BLOCK) {
        const int c  = idx >> 4;       // B row
        const int cc = idx & 15;       // 16B chunk within row
        const float4 v = reinterpret_cast<const float4*>(Bg)[idx];
        const int x  = cc ^ (c & 7);   // swizzled chunk
        *reinterpret_cast<float4*>(&Blds[c * DIM + x * 4]) = v;
    }

    // ---- A rows r-1, r, r+1 (cells r, r+1, r+2) into registers + norms ----
    float4 Aa[16], Ab[16], Ac[16];
    float  anA = 0.f, anB = 0.f, anC = 0.f;
    {
        const int ra = min(max(r - 1, 0), T_LEN - 1);
        const int rb = min(max(r,     0), T_LEN - 1);
        const int rc = min(max(r + 1, 0), T_LEN - 1);
        const float4* __restrict__ pa = reinterpret_cast<const float4*>(Ag + (size_t)ra * DIM);
        const float4* __restrict__ pb = reinterpret_cast<const float4*>(Ag + (size_t)rb * DIM);
        const float4* __restrict__ pc = reinterpret_cast<const float4*>(Ag + (size_t)rc * DIM);
        #pragma unroll
        for (int cc = 0; cc < 16; ++cc) {
            Aa[cc] = pa[cc];
            Ab[cc] = pb[cc];
            Ac[cc] = pc[cc];
            anA += Aa[cc].x*Aa[cc].x + Aa[cc].y*Aa[cc].y + Aa[cc].z*Aa[cc].z + Aa[cc].w*Aa[cc].w;
            anB += Ab[cc].x*Ab[cc].x + Ab[cc].y*Ab[cc].y + Ab[cc].z*Ab[cc].z + Ab[cc].w*Ab[cc].w;
            anC += Ac[cc].x*Ac[cc].x + Ac[cc].y*Ac[cc].y + Ac[cc].z*Ac[cc].z + Ac[cc].w*Ac[cc].w;
        }
    }
    __syncthreads();   // B resident

    // ---- ||B_c||^2 from LDS (lane c reads its own row; conflict-free) ----
    if (tid < T_LEN) {
        const int c = tid;
        float s = 0.f;
        #pragma unroll
        for (int cc = 0; cc < 16; ++cc) {
            const float4 b = *reinterpret_cast<const float4*>(
                &Blds[c * DIM + ((cc ^ (c & 7)) * 4)]);
            s += b.x*b.x + b.y*b.y + b.z*b.z + b.w*b.w;
        }
        bnorm[c] = s;
    }

    // ---- init diag buffers 0 (R[0][0]=0, rest BIG) and 1 (all BIG) ----
    for (int idx = tid; idx <= T_LEN; idx += BLOCK) {
        Rbuf[0][idx] = (idx == 0) ? 0.f : BIGV;
        Rbuf[1][idx] = BIGV;
    }
    __syncthreads();

    const int la = lens[anchor];       // [200, 400]
    const int lb = lens[p];
    const int kt = la + lb;            // target diag, [400, 800]
    const int P  = (kt + 1) / 3;       // phases: diags 2 .. 3P+1 >= kt
    float saved = 0.f;
    bool  have  = false;
    const float NIG = -1.0f / GAMMA;

    for (int ph = 1; ph <= P; ++ph) {
        const int  k     = 3 * ph - 1;          // cellA diag (B: k+1, C: k+2)
        const int  c     = k - r - 1;           // shared B row = j-1
        const bool guard = (c >= 0) && (c < lb) && (r <= la);

        float p2s = BIGV, p1s = BIGV, p1vr = BIGV, bn = 0.f;
        float dA = 0.f, dB = 0.f, dC = 0.f;
        if (guard) {
            const int rm1 = max(r - 1, 0), rc0 = max(r, 0);
            p2s  = Rbuf[(k - 2) & 7][rm1];      // R[r-1][j-1] (valid when r>=1)
            p1s  = Rbuf[(k - 1) & 7][rm1];      // R[r-1][j]
            p1vr = Rbuf[(k - 1) & 7][rc0];      // R[r][j-1]
            bn   = bnorm[c];
            const float* __restrict__ Brow = &Blds[c * DIM];
            const int xr = (c & 7) * 4;         // float-index XOR swizzle
            #pragma unroll
            for (int cc = 0; cc < 16; ++cc) {
                const float4 b = *reinterpret_cast<const float4*>(&Brow[(cc * 4) ^ xr]);
                dA = fmaf(Aa[cc].x, b.x, dA); dB = fmaf(Ab[cc].x, b.x, dB); dC = fmaf(Ac[cc].x, b.x, dC);
                dA = fmaf(Aa[cc].y, b.y, dA); dB = fmaf(Ab[cc].y, b.y, dB); dC = fmaf(Ac[cc].y, b.y, dC);
                dA = fmaf(Aa[cc].z, b.z, dA); dB = fmaf(Ab[cc].z, b.z, dB); dC = fmaf(Ac[cc].z, b.z, dC);
                dA = fmaf(Aa[cc].w, b.w, dA); dB = fmaf(Ab[cc].w, b.w, dB); dC = fmaf(Ac[cc].w, b.w, dC);
            }
        }

        // ---- cellA = (r, j) ----
        float vA = BIGV;
        if (guard && (r >= 1)) {
            const float a  = p2s  * NIG;
            const float b2 = p1s  * NIG;
            const float c2 = p1vr * NIG;
            float m = fmaxf(fmaxf(a, b2), c2);
            float s = __expf(a - m) + __expf(b2 - m) + __expf(c2 - m);
            vA = (anA + bn - 2.f * dA) - GAMMA * (__logf(s) + m);
        }
        const float vAn = __shfl_down(vA, 1);   // R[r+1][j-1] (lane l+1's cellA)

        // ---- cellB = (r+1, j): p2=p1vr, p1s=vA, p1v=vAn ----
        float vB = BIGV;
        if (guard && (r + 1 >= 1) && (r + 1 <= la)) {
            const float a  = p1vr * NIG;
            const float b2 = vA   * NIG;
            const float c2 = vAn  * NIG;
            float m = fmaxf(fmaxf(a, b2), c2);
            float s = __expf(a - m) + __expf(b2 - m) + __expf(c2 - m);
            vB = (anB + bn - 2.f * dB) - GAMMA * (__logf(s) + m);
        }
        const float vBn = __shfl_down(vB, 1);   // R[r+2][j-1] (lane l+1's cellB)

        // ---- cellC = (r+2, j): p2=vAn, p1s=vB, p1v=vBn ----
        float vC = BIGV;
        if (guard && (r + 2 <= la)) {
            const float a  = vAn * NIG;
            const float b2 = vB  * NIG;
            const float c2 = vBn * NIG;
            float m = fmaxf(fmaxf(a, b2), c2);
            float s = __expf(a - m) + __expf(b2 - m) + __expf(c2 - m);
            vC = (anC + bn - 2.f * dC) - GAMMA * (__logf(s) + m);
        }

        // ---- writes & captures: primary lanes only (l < 62) ----
        if (l < 62) {
            if (r >= 0 && r     <= T_LEN) Rbuf[ k      & 7][r]     = vA;
            if (           r + 1 <= T_LEN) Rbuf[(k + 1) & 7][r + 1] = vB;
            if (           r + 2 <= T_LEN) Rbuf[(k + 2) & 7][r + 2] = vC;
            if (k     == kt && r     == la) { saved = vA; have = true; }
            if (k + 1 == kt && r + 1 == la) { saved = vB; have = true; }
            if (k + 2 == kt && r + 2 == la) { saved = vC; have = true; }
        }
        if (tid == BLOCK - 1) Rbuf[(k + 2) & 7][0] = BIGV;   // R[0][k+2] boundary
        __syncthreads();
    }

    if (have) dists[p] = saved / (float)kt;
}

// ---------------------------------------------------------------------------
// Loss epilogue (one wave). Exact-zero semantics of `nz` preserved.
// ---------------------------------------------------------------------------
__global__ void loss_kernel(const float* __restrict__ dists,
                            const float* __restrict__ margin,
                            float* __restrict__ out)
{
    const int g = threadIdx.x;
    float lv = 0.f;
    if (g < NWG) {
        const float* __restrict__ d = dists + g * NSTEP;
        const float aa = d[0];
        const float mg = margin[0];
        float s = 0.f;
        int   nz = 1;
        #pragma unroll
        for (int j = 1; j <= NGE; ++j) {
            const float v = d[j] - aa;
            s += v;
            nz += (v != 0.f);
        }
        #pragma unroll
        for (int j = 1 + NGE; j < NSTEP; ++j) {
            float v = mg - (d[j] - aa);
            v = fmaxf(v, 0.f);
            s += v;
            nz += (v != 0.f);
        }
        lv = s / (float)nz;
    }
    lv += __shfl_down(lv, 8);
    lv += __shfl_down(lv, 4);
    lv += __shfl_down(lv, 2);
    lv += __shfl_down(lv, 1);
    if (g == 0) out[0] = lv / (float)NWG;
}

extern "C" void kernel_launch(void* const* d_in, const int* in_sizes, int n_in,
                              void* d_out, int out_size, void* d_ws, size_t ws_size,
                              hipStream_t stream) {
    const float* data   = (const float*)d_in[0];
    const float* margin = (const float*)d_in[1];
    const int*   lens   = (const int*)d_in[2];
    float* dists = (float*)d_ws;          // 256 floats of scratch

    sdtw_kernel<<<NWG * NSTEP, BLOCK, 0, stream>>>(data, lens, dists);
    loss_kernel<<<1, 64, 0, stream>>>(dists, margin, (float*)d_out);
}